// Round 1
// baseline (474.865 us; speedup 1.0000x reference)
//
#include <hip/hip_runtime.h>
#include <cmath>

#define NPTS 262144
#define NLVL 16
#define TBL  524288u
#define TMASK 524287u

struct ResArr { float r[NLVL]; };

__global__ __launch_bounds__(256) void nerf_fused(
    const float* __restrict__ coords,
    const float* __restrict__ dirs,
    const float* __restrict__ emb,
    const float* __restrict__ dw1, const float* __restrict__ db1,
    const float* __restrict__ dw2, const float* __restrict__ db2,
    const float* __restrict__ cw1, const float* __restrict__ cb1,
    const float* __restrict__ cw2, const float* __restrict__ cb2,
    const float* __restrict__ cw3, const float* __restrict__ cb3,
    const float* __restrict__ cw4, const float* __restrict__ cb4,
    float* __restrict__ out, ResArr res)
{
    const int i = blockIdx.x * 256 + threadIdx.x;

    const float cx = coords[3*i+0], cy = coords[3*i+1], cz = coords[3*i+2];
    const float2* __restrict__ emb2 = reinterpret_cast<const float2*>(emb);

    // ---------------- hash-grid encode ----------------
    float feat[2*NLVL];
    #pragma unroll
    for (int l = 0; l < NLVL; ++l) {
        const float r = res.r[l];
        const float px = cx*r, py = cy*r, pz = cz*r;
        const float fpx = floorf(px), fpy = floorf(py), fpz = floorf(pz);
        const float fx = px - fpx, fy = py - fpy, fz = pz - fpz;
        const unsigned ix = (unsigned)fpx, iy = (unsigned)fpy, iz = (unsigned)fpz;
        const unsigned hx0 = ix,                 hx1 = ix + 1u;                 // prime 1
        const unsigned hy0 = iy * 2654435761u,   hy1 = (iy+1u) * 2654435761u;   // prime 2
        const unsigned hz0 = iz * 805459861u,    hz1 = (iz+1u) * 805459861u;    // prime 3
        const unsigned base = (unsigned)l * TBL;

        const float2 f000 = emb2[base + ((hx0^hy0^hz0) & TMASK)];
        const float2 f001 = emb2[base + ((hx0^hy0^hz1) & TMASK)];
        const float2 f010 = emb2[base + ((hx0^hy1^hz0) & TMASK)];
        const float2 f011 = emb2[base + ((hx0^hy1^hz1) & TMASK)];
        const float2 f100 = emb2[base + ((hx1^hy0^hz0) & TMASK)];
        const float2 f101 = emb2[base + ((hx1^hy0^hz1) & TMASK)];
        const float2 f110 = emb2[base + ((hx1^hy1^hz0) & TMASK)];
        const float2 f111 = emb2[base + ((hx1^hy1^hz1) & TMASK)];

        const float wx0 = 1.f-fx, wx1 = fx;
        const float wy0 = 1.f-fy, wy1 = fy;
        const float wz0 = 1.f-fz, wz1 = fz;
        const float w000 = wx0*wy0*wz0, w001 = wx0*wy0*wz1;
        const float w010 = wx0*wy1*wz0, w011 = wx0*wy1*wz1;
        const float w100 = wx1*wy0*wz0, w101 = wx1*wy0*wz1;
        const float w110 = wx1*wy1*wz0, w111 = wx1*wy1*wz1;

        float o0 = w000*f000.x;          float o1 = w000*f000.y;
        o0 = fmaf(w001, f001.x, o0);     o1 = fmaf(w001, f001.y, o1);
        o0 = fmaf(w010, f010.x, o0);     o1 = fmaf(w010, f010.y, o1);
        o0 = fmaf(w011, f011.x, o0);     o1 = fmaf(w011, f011.y, o1);
        o0 = fmaf(w100, f100.x, o0);     o1 = fmaf(w100, f100.y, o1);
        o0 = fmaf(w101, f101.x, o0);     o1 = fmaf(w101, f101.y, o1);
        o0 = fmaf(w110, f110.x, o0);     o1 = fmaf(w110, f110.y, o1);
        o0 = fmaf(w111, f111.x, o0);     o1 = fmaf(w111, f111.y, o1);
        feat[2*l+0] = o0;
        feat[2*l+1] = o1;
    }

    // ---------------- density MLP: 32 -> 64 (relu) -> 16 ----------------
    float h[64];
    #pragma unroll
    for (int j = 0; j < 64; ++j) h[j] = db1[j];
    #pragma unroll
    for (int k = 0; k < 32; ++k) {
        const float a = feat[k];
        #pragma unroll
        for (int j = 0; j < 64; ++j) h[j] = fmaf(a, dw1[64*k+j], h[j]);
    }
    #pragma unroll
    for (int j = 0; j < 64; ++j) h[j] = fmaxf(h[j], 0.f);

    float dob[16];
    #pragma unroll
    for (int j = 0; j < 16; ++j) dob[j] = db2[j];
    #pragma unroll
    for (int k = 0; k < 64; ++k) {
        const float a = h[k];
        #pragma unroll
        for (int j = 0; j < 16; ++j) dob[j] = fmaf(a, dw2[16*k+j], dob[j]);
    }

    // ---------------- SH encode (deg 4) on normalized direction ----------------
    const float dxr = dirs[3*i+0], dyr = dirs[3*i+1], dzr = dirs[3*i+2];
    const float inv = 1.f / sqrtf(dxr*dxr + dyr*dyr + dzr*dzr);
    float x = dxr*inv, y = dyr*inv, z = dzr*inv;
    // replicate reference's (d+1)/2 * 2 - 1 rounding chain
    x = ((x + 1.f) * 0.5f) * 2.f - 1.f;
    y = ((y + 1.f) * 0.5f) * 2.f - 1.f;
    z = ((z + 1.f) * 0.5f) * 2.f - 1.f;
    const float xx = x*x, yy = y*y, zz = z*z;
    const float xy = x*y, yz = y*z, xz = x*z;

    float inp[32];
    inp[0]  = 0.28209479177387814f;
    inp[1]  = -0.48860251190291987f * y;
    inp[2]  =  0.48860251190291987f * z;
    inp[3]  = -0.48860251190291987f * x;
    inp[4]  =  1.0925484305920792f  * xy;
    inp[5]  = -1.0925484305920792f  * yz;
    inp[6]  =  0.94617469575756f * zz - 0.31539156525252f;
    inp[7]  = -1.0925484305920792f  * xz;
    inp[8]  =  0.5462742152960396f  * (xx - yy);
    inp[9]  =  0.5900435899266435f  * y * (-3.f*xx + yy);
    inp[10] =  2.890611442640554f   * xy * z;
    inp[11] =  0.4570457994644657f  * y * (1.f - 5.f*zz);
    inp[12] =  0.3731763325901154f  * z * (5.f*zz - 3.f);
    inp[13] =  0.4570457994644657f  * x * (1.f - 5.f*zz);
    inp[14] =  1.445305721320277f   * z * (xx - yy);
    inp[15] =  0.5900435899266435f  * x * (xx - 3.f*yy);
    #pragma unroll
    for (int j = 0; j < 16; ++j) inp[16+j] = dob[j];

    // ---------------- color MLP: 32 -> 64 -> 64 -> 64 -> 3 ----------------
    float xa[64], xb[64];
    #pragma unroll
    for (int j = 0; j < 64; ++j) xa[j] = cb1[j];
    #pragma unroll
    for (int k = 0; k < 32; ++k) {
        const float a = inp[k];
        #pragma unroll
        for (int j = 0; j < 64; ++j) xa[j] = fmaf(a, cw1[64*k+j], xa[j]);
    }
    #pragma unroll
    for (int j = 0; j < 64; ++j) xa[j] = fmaxf(xa[j], 0.f);

    #pragma unroll
    for (int j = 0; j < 64; ++j) xb[j] = cb2[j];
    #pragma unroll
    for (int k = 0; k < 64; ++k) {
        const float a = xa[k];
        #pragma unroll
        for (int j = 0; j < 64; ++j) xb[j] = fmaf(a, cw2[64*k+j], xb[j]);
    }
    #pragma unroll
    for (int j = 0; j < 64; ++j) xb[j] = fmaxf(xb[j], 0.f);

    #pragma unroll
    for (int j = 0; j < 64; ++j) xa[j] = cb3[j];
    #pragma unroll
    for (int k = 0; k < 64; ++k) {
        const float a = xb[k];
        #pragma unroll
        for (int j = 0; j < 64; ++j) xa[j] = fmaf(a, cw3[64*k+j], xa[j]);
    }
    #pragma unroll
    for (int j = 0; j < 64; ++j) xa[j] = fmaxf(xa[j], 0.f);

    float c0 = cb4[0], c1 = cb4[1], c2 = cb4[2];
    #pragma unroll
    for (int k = 0; k < 64; ++k) {
        const float a = xa[k];
        c0 = fmaf(a, cw4[3*k+0], c0);
        c1 = fmaf(a, cw4[3*k+1], c1);
        c2 = fmaf(a, cw4[3*k+2], c2);
    }

    // ---------------- outputs: [density(B), color(B,3)] ----------------
    out[i] = expf(dob[0]);
    out[NPTS + 3*i + 0] = 1.f / (1.f + expf(-c0));
    out[NPTS + 3*i + 1] = 1.f / (1.f + expf(-c1));
    out[NPTS + 3*i + 2] = 1.f / (1.f + expf(-c2));
}

extern "C" void kernel_launch(void* const* d_in, const int* in_sizes, int n_in,
                              void* d_out, int out_size, void* d_ws, size_t ws_size,
                              hipStream_t stream)
{
    // RES must bit-match numpy: floor(16 * (exp((log512-log16)/15))**l) in f64.
    // Values land exactly on 32/64/128/256/512 — replicate with the same libm.
    ResArr res;
    const double b = exp((log(512.0) - log(16.0)) / 15.0);
    for (int l = 0; l < NLVL; ++l)
        res.r[l] = (float)floor(16.0 * pow(b, (double)l));

    nerf_fused<<<NPTS/256, 256, 0, stream>>>(
        (const float*)d_in[0],  // coords
        (const float*)d_in[1],  // directions
        (const float*)d_in[2],  // embeddings
        (const float*)d_in[3],  (const float*)d_in[4],   // dw1, db1
        (const float*)d_in[5],  (const float*)d_in[6],   // dw2, db2
        (const float*)d_in[7],  (const float*)d_in[8],   // cw1, cb1
        (const float*)d_in[9],  (const float*)d_in[10],  // cw2, cb2
        (const float*)d_in[11], (const float*)d_in[12],  // cw3, cb3
        (const float*)d_in[13], (const float*)d_in[14],  // cw4, cb4
        (float*)d_out, res);
}